// Round 9
// baseline (188.413 us; speedup 1.0000x reference)
//
#include <hip/hip_runtime.h>
#include <math.h>

// Non-local attention: X [8, 64, 64, 64] fp32.
// Per batch b: Q=K=V = X_b^T  [S=4096, D=64];  out = softmax(Q K^T) V, stored [b][c][s].
//
// R9 = R8 minus K/V LDS staging: all K/V MFMA fragments are direct contiguous 16B
// global loads (L1/L2-resident prepass arrays). Zero-barrier K-loop (sP wave-private),
// LDS 17.4KB/block. Split-K x4, 2 waves x 32 Q rows, raw v_exp_f32 softmax with the
// fixed Cauchy-Schwarz bound folded into the MFMA C-init.

#define SEQ 4096
#define DIM 64
#define LDB 72
#define LDO 68
#define QSCALE 1.2011224087864498f   // sqrt(log2(e))

typedef __attribute__((ext_vector_type(8))) short  short8;
typedef __attribute__((ext_vector_type(4))) float  f32x4;

__device__ __forceinline__ unsigned short f2bf(float f) {
    union { float f; unsigned int u; } x; x.f = f;
    unsigned int u = x.u + 0x7FFFu + ((x.u >> 16) & 1u);
    return (unsigned short)(u >> 16);
}
__device__ __forceinline__ float bf2f(unsigned short h) {
    union { unsigned int u; float f; } x; x.u = ((unsigned int)h) << 16; return x.f;
}
__device__ __forceinline__ float fast_exp2(float x) {
#if __has_builtin(__builtin_amdgcn_exp2f)
    return __builtin_amdgcn_exp2f(x);
#else
    float r;
    asm("v_exp_f32 %0, %1\n\ts_nop 0" : "=v"(r) : "v"(x));
    return r;
#endif
}
__device__ __forceinline__ float fast_rcp(float x) {
#if __has_builtin(__builtin_amdgcn_rcpf)
    return __builtin_amdgcn_rcpf(x);
#else
    return 1.f / x;
#endif
}

#define LDT 68
__global__ __launch_bounds__(256) void prepass3(const float* __restrict__ X,
                                                unsigned short* __restrict__ Xbf,
                                                unsigned short* __restrict__ XbfT,
                                                float* __restrict__ Norms,
                                                float* __restrict__ MaxPart) {
    __shared__ __align__(16) unsigned short sT[64 * LDT];
    __shared__ float sRed[4];
    const int b = blockIdx.y, m0 = blockIdx.x * 64;
    const float* Xb = X + (size_t)b * DIM * SEQ;
    unsigned short* Bb = Xbf  + (size_t)b * DIM * SEQ;
    unsigned short* Tb = XbfT + (size_t)b * SEQ * DIM;
    const int t = threadIdx.x, w = t >> 6;
    const int mw = t & 15, cg = t >> 4;

    #pragma unroll
    for (int cr = 0; cr < 4; ++cr) {
        const int c = cg * 4 + cr;
        const f32x4 v = *(const f32x4*)(Xb + (size_t)c * SEQ + m0 + 4 * mw);
        *(ushort4*)(Bb + (size_t)c * SEQ + m0 + 4 * mw) =
            make_ushort4(f2bf(v.x), f2bf(v.y), f2bf(v.z), f2bf(v.w));
        sT[(4 * mw + 0) * LDT + c] = f2bf(v.x * QSCALE);
        sT[(4 * mw + 1) * LDT + c] = f2bf(v.y * QSCALE);
        sT[(4 * mw + 2) * LDT + c] = f2bf(v.z * QSCALE);
        sT[(4 * mw + 3) * LDT + c] = f2bf(v.w * QSCALE);
    }
    __syncthreads();
    const int m = t >> 2, ck = t & 3;
    const short8 a0 = *(const short8*)(sT + m * LDT + ck * 16);
    const short8 a1 = *(const short8*)(sT + m * LDT + ck * 16 + 8);
    *(short8*)(Tb + (size_t)(m0 + m) * DIM + ck * 16)     = a0;
    *(short8*)(Tb + (size_t)(m0 + m) * DIM + ck * 16 + 8) = a1;
    float s = 0.f;
    #pragma unroll
    for (int i = 0; i < 8; ++i) {
        const float f0 = bf2f((unsigned short)a0[i]);
        const float f1 = bf2f((unsigned short)a1[i]);
        s += f0 * f0 + f1 * f1;
    }
    s += __shfl_xor(s, 1);
    s += __shfl_xor(s, 2);
    const float nm = sqrtf(s);
    if (ck == 0) Norms[(size_t)b * SEQ + m0 + m] = nm;
    float mx = nm;
    #pragma unroll
    for (int d = 4; d < 64; d <<= 1) mx = fmaxf(mx, __shfl_xor(mx, d));
    if ((t & 63) == 0) sRed[w] = mx;
    __syncthreads();
    if (t == 0)
        MaxPart[b * 64 + blockIdx.x] =
            fmaxf(fmaxf(sRed[0], sRed[1]), fmaxf(sRed[2], sRed[3]));
}

// BN=32 flash kernel, 2 waves x 32 Q rows, split-K x4. Direct-global K/V frags.
// LDS: sP 4KB (wave-private, first bytes of the 17.4KB epilogue buffer).
template <bool PARTIAL>
__global__ __launch_bounds__(128, 4) void attn_split4(const unsigned short* __restrict__ Xbf,
                                                      const unsigned short* __restrict__ XbfT,
                                                      const float* __restrict__ Norms,
                                                      const float* __restrict__ MaxPart,
                                                      unsigned short* __restrict__ Obf,  // PARTIAL
                                                      float* __restrict__ Lbase,         // PARTIAL
                                                      float* __restrict__ Out,           // !PARTIAL
                                                      int niter) {
    __shared__ __align__(16) unsigned char smem[17408];
    unsigned short* sP = (unsigned short*)smem;   // [wave][row n 0..31][32 shorts]
    float*          sO = (float*)smem;            // epilogue overlay (64 x LDO fp32)

    const int tid  = threadIdx.x;
    const int lane = tid & 63;
    const int w    = tid >> 6;
    const int l15  = lane & 15;
    const int quad = lane >> 4;

    const int b   = blockIdx.y;
    const int s0  = blockIdx.x * 64;
    const int h   = blockIdx.z;
    const int kt0 = h * niter;
    const unsigned short* Bb = Xbf  + (size_t)b * DIM * SEQ;
    const unsigned short* Tb = XbfT + (size_t)b * SEQ * DIM;

    float mxn = MaxPart[b * 64 + lane];
    #pragma unroll
    for (int d = 1; d < 64; d <<= 1) mxn = fmaxf(mxn, __shfl_xor(mxn, d));

    short8 qf[2][2];
    f32x4 cin[2];
    #pragma unroll
    for (int qt = 0; qt < 2; ++qt) {
        const int row = s0 + 32 * w + 16 * qt + l15;
        const unsigned short* qp = Tb + (size_t)row * DIM + quad * 8;
        qf[qt][0] = *(const short8*)(qp);
        qf[qt][1] = *(const short8*)(qp + 32);
        const float mrow = Norms[(size_t)b * SEQ + row] * mxn;
        cin[qt] = (f32x4){-mrow, -mrow, -mrow, -mrow};
    }

    f32x4 acc_o[2][4];
    #pragma unroll
    for (int qt = 0; qt < 2; ++qt)
        #pragma unroll
        for (int ct = 0; ct < 4; ++ct) acc_o[qt][ct] = (f32x4){0.f, 0.f, 0.f, 0.f};
    f32x4 lp4[2];
    lp4[0] = (f32x4){0.f, 0.f, 0.f, 0.f};
    lp4[1] = (f32x4){0.f, 0.f, 0.f, 0.f};

    // ---- P LDS addresses (wave-private; same swizzle as R8, verified) ----
    const int vkey = (l15 & 3) ^ (l15 >> 2);
    unsigned short* const prow = sP + (w << 10) + (l15 << 5);     // +qt*512
    unsigned short* pw[2];
    #pragma unroll
    for (int mt = 0; mt < 2; ++mt)
        pw[mt] = prow + ((((2 * mt + (quad >> 1)) ^ vkey) << 3) + ((quad & 1) << 2));
    const unsigned short* pr = prow + ((quad ^ vkey) << 3);

    // ---- direct-global fragment pointers (contiguous 16B per lane) ----
    // K frag: A[m=key][k=dim]: row kt*32+16mt+l15 of XbfT, dim chunk (quad*8 + 32ks)
    const unsigned short* kp = Tb + (size_t)(kt0 * 32 + l15) * DIM + quad * 8;
    // V frag: B[k=key][n=chan]: row chan=16ct+l15 of Xbf, keys kt*32+quad*8..+8
    const unsigned short* vp[4];
    #pragma unroll
    for (int ct = 0; ct < 4; ++ct)
        vp[ct] = Bb + (size_t)(16 * ct + l15) * SEQ + kt0 * 32 + quad * 8;

    for (int it = 0; it < niter; ++it) {
        // K loads first (consumed first -> waitcnt leaves V in flight), then V
        short8 kf[2][2], vf[4];
        #pragma unroll
        for (int mt = 0; mt < 2; ++mt)
            #pragma unroll
            for (int ks = 0; ks < 2; ++ks)
                kf[ks][mt] = *(const short8*)(kp + mt * 1024 + ks * 32);
        #pragma unroll
        for (int ct = 0; ct < 4; ++ct)
            vf[ct] = *(const short8*)(vp[ct]);

        // phase 1: all S-MFMAs (8)
        f32x4 a[2][2];
        #pragma unroll
        for (int qt = 0; qt < 2; ++qt)
            #pragma unroll
            for (int mt = 0; mt < 2; ++mt) {
                f32x4 s = cin[qt];
                s = __builtin_amdgcn_mfma_f32_16x16x32_bf16(kf[0][mt], qf[qt][0], s, 0, 0, 0);
                s = __builtin_amdgcn_mfma_f32_16x16x32_bf16(kf[1][mt], qf[qt][1], s, 0, 0, 0);
                a[qt][mt] = s;
            }
        // phase 2: exps + packs + lp partials + P-writes
        #pragma unroll
        for (int qt = 0; qt < 2; ++qt)
            #pragma unroll
            for (int mt = 0; mt < 2; ++mt) {
                const float p0 = fast_exp2(a[qt][mt][0]);
                const float p1 = fast_exp2(a[qt][mt][1]);
                const float p2 = fast_exp2(a[qt][mt][2]);
                const float p3 = fast_exp2(a[qt][mt][3]);
                lp4[qt] += (f32x4){p0, p1, p2, p3};
                const unsigned lo = __builtin_amdgcn_perm(__float_as_uint(p1), __float_as_uint(p0), 0x07060302u);
                const unsigned hi = __builtin_amdgcn_perm(__float_as_uint(p3), __float_as_uint(p2), 0x07060302u);
                *(uint2*)(pw[mt] + qt * 512) = make_uint2(lo, hi);
            }
        // phase 3: P reads, then all PV-MFMAs (8)
        short8 pf[2];
        #pragma unroll
        for (int qt = 0; qt < 2; ++qt)
            pf[qt] = *(const short8*)(pr + qt * 512);
        #pragma unroll
        for (int qt = 0; qt < 2; ++qt)
            #pragma unroll
            for (int ct = 0; ct < 4; ++ct)
                acc_o[qt][ct] = __builtin_amdgcn_mfma_f32_16x16x32_bf16(pf[qt], vf[ct], acc_o[qt][ct], 0, 0, 0);

        kp += 2048;                 // 32 rows x 64 shorts
        #pragma unroll
        for (int ct = 0; ct < 4; ++ct) vp[ct] += 32;
    }

    float lp[2];
    #pragma unroll
    for (int qt = 0; qt < 2; ++qt) {
        lp[qt] = (lp4[qt][0] + lp4[qt][1]) + (lp4[qt][2] + lp4[qt][3]);
        lp[qt] += __shfl_xor(lp[qt], 16);
        lp[qt] += __shfl_xor(lp[qt], 32);
    }

    if (PARTIAL) {
        if (quad == 0) {
            #pragma unroll
            for (int qt = 0; qt < 2; ++qt)
                (Lbase + (size_t)h * 8 * SEQ)[(size_t)b * SEQ + s0 + 32 * w + 16 * qt + l15] = lp[qt];
        }
    } else {
        #pragma unroll
        for (int qt = 0; qt < 2; ++qt) {
            float inv[4];
            #pragma unroll
            for (int r = 0; r < 4; ++r) inv[r] = fast_rcp(__shfl(lp[qt], 4 * quad + r));
            #pragma unroll
            for (int ct = 0; ct < 4; ++ct)
                #pragma unroll
                for (int r = 0; r < 4; ++r) acc_o[qt][ct][r] *= inv[r];
        }
    }

    __syncthreads();   // all waves done with sP before sO overlay writes
    #pragma unroll
    for (int qt = 0; qt < 2; ++qt)
        #pragma unroll
        for (int ct = 0; ct < 4; ++ct) {
            const int c = 16 * ct + l15;
            #pragma unroll
            for (int r = 0; r < 4; ++r)
                sO[c * LDO + 32 * w + 16 * qt + 4 * quad + r] = acc_o[qt][ct][r];
        }
    __syncthreads();
    const int mw = tid & 15, cg = tid >> 4;
    if (PARTIAL) {
        unsigned short* Op = Obf + (size_t)h * 8 * DIM * SEQ;
        #pragma unroll
        for (int cc = 0; cc < 8; ++cc) {
            const int c = cg + 8 * cc;
            const f32x4 v = *(const f32x4*)(sO + c * LDO + 4 * mw);
            *(ushort4*)(Op + ((size_t)b * DIM + c) * SEQ + s0 + 4 * mw) =
                make_ushort4(f2bf(v.x), f2bf(v.y), f2bf(v.z), f2bf(v.w));
        }
    } else {
        #pragma unroll
        for (int cc = 0; cc < 8; ++cc) {
            const int c = cg + 8 * cc;
            const f32x4 v = *(const f32x4*)(sO + c * LDO + 4 * mw);
            *(f32x4*)(Out + ((size_t)b * DIM + c) * SEQ + s0 + 4 * mw) = v;
        }
    }
}

__global__ __launch_bounds__(256) void combine4(const unsigned short* __restrict__ Obf,
                                                const float* __restrict__ Lp,
                                                float* __restrict__ Out) {
    const int gid = blockIdx.x * 256 + threadIdx.x;
    const size_t base = (size_t)gid * 4;
    const int s = (int)(base & 4095);
    const int b = (int)(base >> 18);
    f32x4 os = (f32x4){0.f, 0.f, 0.f, 0.f};
    f32x4 ls = (f32x4){0.f, 0.f, 0.f, 0.f};
    #pragma unroll
    for (int h = 0; h < 4; ++h) {
        const ushort4 o = *(const ushort4*)(Obf + (size_t)h * 2097152 + base);
        os[0] += bf2f(o.x); os[1] += bf2f(o.y); os[2] += bf2f(o.z); os[3] += bf2f(o.w);
        const f32x4 l = *(const f32x4*)(Lp + (size_t)h * 8 * SEQ + b * SEQ + s);
        #pragma unroll
        for (int i = 0; i < 4; ++i) ls[i] += l[i];
    }
    f32x4 o;
    #pragma unroll
    for (int i = 0; i < 4; ++i) o[i] = os[i] / ls[i];
    *(f32x4*)(Out + base) = o;
}

__global__ __launch_bounds__(256, 2) void attn_fallback(const float* __restrict__ X,
                                                        float* __restrict__ Out) {
    __shared__ __align__(16) unsigned char smem[27648];
    unsigned short* sK = (unsigned short*)smem;
    unsigned short* sV = (unsigned short*)(smem + 9216);
    unsigned short* sP = (unsigned short*)(smem + 18432);
    float*          sO = (float*)smem;
    const int tid  = threadIdx.x;
    const int lane = tid & 63;
    const int w    = tid >> 6;
    const int l15  = lane & 15;
    const int quad = lane >> 4;
    const int b  = blockIdx.y;
    const int s0 = blockIdx.x * 64;
    const float* Xb = X + (size_t)b * DIM * SEQ;
    const int mgrp = tid & 15;
    const int c0   = tid >> 4;

    for (int cc = 0; cc < 4; ++cc) {
        int c = c0 + 16 * cc;
        const f32x4 v = *(const f32x4*)(Xb + (size_t)c * SEQ + s0 + 4 * mgrp);
        sK[(4 * mgrp + 0) * LDB + c] = f2bf(v.x);
        sK[(4 * mgrp + 1) * LDB + c] = f2bf(v.y);
        sK[(4 * mgrp + 2) * LDB + c] = f2bf(v.z);
        sK[(4 * mgrp + 3) * LDB + c] = f2bf(v.w);
    }
    __syncthreads();
    short8 qf0, qf1;
    {
        const int row = 16 * w + l15;
        qf0 = *(const short8*)(sK + row * LDB + quad * 8);
        qf1 = *(const short8*)(sK + row * LDB + 32 + quad * 8);
    }
    __syncthreads();
    f32x4 acc_o[4];
    for (int ct = 0; ct < 4; ++ct) acc_o[ct] = (f32x4){0.f, 0.f, 0.f, 0.f};
    float m_i[4] = {-1e30f, -1e30f, -1e30f, -1e30f};
    float l_i[4] = {0.f, 0.f, 0.f, 0.f};
    for (int kt = 0; kt < SEQ / 64; ++kt) {
        const int m0 = kt * 64;
        for (int cc = 0; cc < 4; ++cc) {
            int c = c0 + 16 * cc;
            const f32x4 v = *(const f32x4*)(Xb + (size_t)c * SEQ + m0 + 4 * mgrp);
            unsigned short h0 = f2bf(v.x), h1 = f2bf(v.y), h2 = f2bf(v.z), h3 = f2bf(v.w);
            *(ushort4*)(sV + c * LDB + 4 * mgrp) = make_ushort4(h0, h1, h2, h3);
            sK[(4 * mgrp + 0) * LDB + c] = h0;
            sK[(4 * mgrp + 1) * LDB + c] = h1;
            sK[(4 * mgrp + 2) * LDB + c] = h2;
            sK[(4 * mgrp + 3) * LDB + c] = h3;
        }
        __syncthreads();
        short8 vf[2][4];
        for (int ks = 0; ks < 2; ++ks)
            for (int ct = 0; ct < 4; ++ct)
                vf[ks][ct] = *(const short8*)(sV + (16 * ct + l15) * LDB + ks * 32 + quad * 8);
        f32x4 acc_s[4];
        for (int mt = 0; mt < 4; ++mt) {
            const int row = 16 * mt + l15;
            const short8 kf0 = *(const short8*)(sK + row * LDB + quad * 8);
            const short8 kf1 = *(const short8*)(sK + row * LDB + 32 + quad * 8);
            f32x4 a = (f32x4){0.f, 0.f, 0.f, 0.f};
            a = __builtin_amdgcn_mfma_f32_16x16x32_bf16(qf0, kf0, a, 0, 0, 0);
            a = __builtin_amdgcn_mfma_f32_16x16x32_bf16(qf1, kf1, a, 0, 0, 0);
            acc_s[mt] = a;
        }
        float alpha[4];
        for (int r = 0; r < 4; ++r) {
            float mx = fmaxf(fmaxf(acc_s[0][r], acc_s[1][r]), fmaxf(acc_s[2][r], acc_s[3][r]));
            mx = fmaxf(mx, __shfl_xor(mx, 1));
            mx = fmaxf(mx, __shfl_xor(mx, 2));
            mx = fmaxf(mx, __shfl_xor(mx, 4));
            mx = fmaxf(mx, __shfl_xor(mx, 8));
            const float mnew = fmaxf(m_i[r], mx);
            alpha[r] = __expf(m_i[r] - mnew);
            m_i[r] = mnew;
        }
        float rowsum[4] = {0.f, 0.f, 0.f, 0.f};
        unsigned short pb[4][4];
        for (int mt = 0; mt < 4; ++mt)
            for (int r = 0; r < 4; ++r) {
                const float p = __expf(acc_s[mt][r] - m_i[r]);
                rowsum[r] += p;
                pb[mt][r] = f2bf(p);
            }
        for (int r = 0; r < 4; ++r) {
            float s = rowsum[r];
            s += __shfl_xor(s, 1);
            s += __shfl_xor(s, 2);
            s += __shfl_xor(s, 4);
            s += __shfl_xor(s, 8);
            l_i[r] = alpha[r] * l_i[r] + s;
        }
        for (int ct = 0; ct < 4; ++ct)
            for (int r = 0; r < 4; ++r)
                acc_o[ct][r] *= alpha[r];
        for (int mt = 0; mt < 4; ++mt)
            for (int r = 0; r < 4; ++r)
                sP[(16 * w + quad * 4 + r) * LDB + l15 + 16 * mt] = pb[mt][r];
        __syncthreads();
        const short8 pf0 = *(const short8*)(sP + (16 * w + l15) * LDB + quad * 8);
        const short8 pf1 = *(const short8*)(sP + (16 * w + l15) * LDB + 32 + quad * 8);
        for (int ct = 0; ct < 4; ++ct) {
            acc_o[ct] = __builtin_amdgcn_mfma_f32_16x16x32_bf16(pf0, vf[0][ct], acc_o[ct], 0, 0, 0);
            acc_o[ct] = __builtin_amdgcn_mfma_f32_16x16x32_bf16(pf1, vf[1][ct], acc_o[ct], 0, 0, 0);
        }
    }
    float inv[4];
    for (int r = 0; r < 4; ++r) inv[r] = 1.f / l_i[r];
    for (int ct = 0; ct < 4; ++ct) {
        const int c = 16 * ct + l15;
        for (int r = 0; r < 4; ++r)
            sO[c * LDO + 16 * w + quad * 4 + r] = acc_o[ct][r] * inv[r];
    }
    __syncthreads();
    for (int cc = 0; cc < 4; ++cc) {
        const int c = c0 + 16 * cc;
        const f32x4 v = *(const f32x4*)(sO + c * LDO + 4 * mgrp);
        *(f32x4*)(Out + (size_t)b * DIM * SEQ + (size_t)c * SEQ + s0 + 4 * mgrp) = v;
    }
}

extern "C" void kernel_launch(void* const* d_in, const int* in_sizes, int n_in,
                              void* d_out, int out_size, void* d_ws, size_t ws_size,
                              hipStream_t stream) {
    const float* X = (const float*)d_in[0];
    float* Out = (float*)d_out;
    const size_t elems = (size_t)8 * SEQ * DIM;               // 2M
    const size_t offXbfT  = elems * 2;                        // Xbf 4MB
    const size_t offNorms = offXbfT + elems * 2;              // 8MB
    const size_t offMaxP  = offNorms + (size_t)8 * SEQ * 4;   // +128KB
    const size_t offObf   = offMaxP + 8 * 64 * 4;             // +2KB
    const size_t offLpart = offObf + 4 * elems * 2;           // +16MB (4 bf16 slabs)
    const size_t need_split = offLpart + 4 * (size_t)8 * SEQ * 4;  // ~24.64MB
    const size_t need_h1    = offObf;

    if (ws_size >= need_h1) {
        unsigned short* Xbf   = (unsigned short*)d_ws;
        unsigned short* XbfT  = (unsigned short*)((char*)d_ws + offXbfT);
        float* Norms   = (float*)((char*)d_ws + offNorms);
        float* MaxPart = (float*)((char*)d_ws + offMaxP);
        prepass3<<<dim3(64, 8), 256, 0, stream>>>(X, Xbf, XbfT, Norms, MaxPart);
        if (ws_size >= need_split) {
            unsigned short* Obf = (unsigned short*)((char*)d_ws + offObf);
            float* Lp = (float*)((char*)d_ws + offLpart);
            attn_split4<true><<<dim3(64, 8, 4), 128, 0, stream>>>(Xbf, XbfT, Norms, MaxPart,
                                                                  Obf, Lp, nullptr, 32);
            combine4<<<(int)(elems / 1024), 256, 0, stream>>>(Obf, Lp, Out);
        } else {
            attn_split4<false><<<dim3(64, 8, 1), 128, 0, stream>>>(Xbf, XbfT, Norms, MaxPart,
                                                                   nullptr, nullptr, Out, 128);
        }
    } else {
        attn_fallback<<<dim3(64, 8), 256, 0, stream>>>(X, Out);
    }
}

// Round 10
// 112.841 us; speedup vs baseline: 1.6697x; 1.6697x over previous
//
#include <hip/hip_runtime.h>
#include <math.h>

// Non-local attention: X [8, 64, 64, 64] fp32.
// Per batch b: Q=K=V = X_b^T  [S=4096, D=64];  out = softmax(Q K^T) V, stored [b][c][s].
//
// R10: fragment-order prepass. Kf/Vf hold each MFMA fragment's 16B in LANE ORDER, so
// every K/V fragment load is one lane-contiguous 1KB coalesced global load (L2-resident
// streams; R9's 16-scattered-line failure mode eliminated). No K/V LDS staging, no
// in-loop barriers (sP wave-private). Split-K x4, 2 waves x 32 Q rows, raw v_exp_f32
// softmax with the fixed Cauchy-Schwarz bound folded into the MFMA C-init.
//
// Kf[b][tile][mt][ks][lane]: scaled bf16, lane(=quad*16+l15) holds
//   XbfT_scaled[tile*32+mt*16+l15][quad*8+32*ks .. +8]   (also serves Q fragments)
// Vf[b][tile][ct][lane]: unscaled bf16, lane holds
//   Xbf[16*ct+l15][tile*32+quad*8 .. +8]

#define SEQ 4096
#define DIM 64
#define LDB 72
#define LDO 68
#define LDS2 68
#define QSCALE 1.2011224087864498f   // sqrt(log2(e))

typedef __attribute__((ext_vector_type(8))) short  short8;
typedef __attribute__((ext_vector_type(4))) float  f32x4;

__device__ __forceinline__ unsigned short f2bf(float f) {
    union { float f; unsigned int u; } x; x.f = f;
    unsigned int u = x.u + 0x7FFFu + ((x.u >> 16) & 1u);
    return (unsigned short)(u >> 16);
}
__device__ __forceinline__ float bf2f(unsigned short h) {
    union { unsigned int u; float f; } x; x.u = ((unsigned int)h) << 16; return x.f;
}
__device__ __forceinline__ float fast_exp2(float x) {
#if __has_builtin(__builtin_amdgcn_exp2f)
    return __builtin_amdgcn_exp2f(x);
#else
    float r;
    asm("v_exp_f32 %0, %1\n\ts_nop 0" : "=v"(r) : "v"(x));
    return r;
#endif
}
__device__ __forceinline__ float fast_rcp(float x) {
#if __has_builtin(__builtin_amdgcn_rcpf)
    return __builtin_amdgcn_rcpf(x);
#else
    return 1.f / x;
#endif
}

// ---------------- prepass: fragment-order bf16 arrays + scaled norms + max partials ----
__global__ __launch_bounds__(256) void prepass4(const float* __restrict__ X,
                                                unsigned short* __restrict__ Kf,
                                                unsigned short* __restrict__ Vf,
                                                float* __restrict__ Norms,
                                                float* __restrict__ MaxPart) {
    __shared__ __align__(16) unsigned short sT[64 * LDS2];    // scaled [m][c]
    __shared__ __align__(16) unsigned short sVu[64 * LDS2];   // unscaled [c][m]
    __shared__ float sRed[4];
    const int b = blockIdx.y, m0 = blockIdx.x * 64;
    const float* Xb = X + (size_t)b * DIM * SEQ;
    const int t = threadIdx.x, w = t >> 6;
    const int mw = t & 15, cg = t >> 4;

    #pragma unroll
    for (int cr = 0; cr < 4; ++cr) {
        const int c = cg * 4 + cr;
        const f32x4 v = *(const f32x4*)(Xb + (size_t)c * SEQ + m0 + 4 * mw);
        *(ushort4*)(sVu + c * LDS2 + 4 * mw) =
            make_ushort4(f2bf(v.x), f2bf(v.y), f2bf(v.z), f2bf(v.w));
        sT[(4 * mw + 0) * LDS2 + c] = f2bf(v.x * QSCALE);
        sT[(4 * mw + 1) * LDS2 + c] = f2bf(v.y * QSCALE);
        sT[(4 * mw + 2) * LDS2 + c] = f2bf(v.z * QSCALE);
        sT[(4 * mw + 3) * LDS2 + c] = f2bf(v.w * QSCALE);
    }
    __syncthreads();
    const int m = t >> 2, ck = t & 3;   // m: key row (for Kf) AND chan row (for Vf)

    // ---- Kf: row m, dim-chunks 2ck and 2ck+1 ----
    const short8 a0 = *(const short8*)(sT + m * LDS2 + ck * 16);
    const short8 a1 = *(const short8*)(sT + m * LDS2 + ck * 16 + 8);
    {
        const size_t base = (size_t)b * 262144 + (size_t)(m0 >> 5) * 2048;  // shorts
        #pragma unroll
        for (int j = 0; j < 2; ++j) {
            const int chunk = 2 * ck + j;
            const int tile = m >> 5, mt = (m >> 4) & 1;
            const int quad = chunk & 3, ks = chunk >> 2;
            const size_t off = base + (size_t)(tile * 4 + mt * 2 + ks) * 512
                                    + (size_t)(quad * 16 + (m & 15)) * 8;
            *(short8*)(Kf + off) = j ? a1 : a0;
        }
    }
    // ---- scaled row norm (from a0/a1), exact C-S bound on scaled scores ----
    float s = 0.f;
    #pragma unroll
    for (int i = 0; i < 8; ++i) {
        const float f0 = bf2f((unsigned short)a0[i]);
        const float f1 = bf2f((unsigned short)a1[i]);
        s += f0 * f0 + f1 * f1;
    }
    s += __shfl_xor(s, 1);
    s += __shfl_xor(s, 2);
    const float nm = sqrtf(s);
    if (ck == 0) Norms[(size_t)b * SEQ + m0 + m] = nm;

    // ---- Vf: chan m, key-chunks 2ck and 2ck+1 ----
    const short8 v0 = *(const short8*)(sVu + m * LDS2 + ck * 16);
    const short8 v1 = *(const short8*)(sVu + m * LDS2 + ck * 16 + 8);
    {
        const size_t base = (size_t)b * 262144;
        #pragma unroll
        for (int j = 0; j < 2; ++j) {
            const int chunk = 2 * ck + j;
            const int tile = chunk >> 2, quad = chunk & 3;
            const size_t off = base + (size_t)((m0 >> 5) + tile) * 2048
                                    + (size_t)((m >> 4) * 64 + quad * 16 + (m & 15)) * 8;
            *(short8*)(Vf + off) = j ? v1 : v0;
        }
    }

    float mx = nm;
    #pragma unroll
    for (int d = 4; d < 64; d <<= 1) mx = fmaxf(mx, __shfl_xor(mx, d));
    if ((t & 63) == 0) sRed[w] = mx;
    __syncthreads();
    if (t == 0)
        MaxPart[b * 64 + blockIdx.x] =
            fmaxf(fmaxf(sRed[0], sRed[1]), fmaxf(sRed[2], sRed[3]));
}

// BN=32 flash kernel, 2 waves x 32 Q rows, split-K x4. Fragment-order global K/V.
template <bool PARTIAL>
__global__ __launch_bounds__(128, 4) void attn_split4(const unsigned short* __restrict__ Kf,
                                                      const unsigned short* __restrict__ Vf,
                                                      const float* __restrict__ Norms,
                                                      const float* __restrict__ MaxPart,
                                                      unsigned short* __restrict__ Obf,  // PARTIAL
                                                      float* __restrict__ Lbase,         // PARTIAL
                                                      float* __restrict__ Out,           // !PARTIAL
                                                      int niter) {
    __shared__ __align__(16) unsigned char smem[17408];
    unsigned short* sP = (unsigned short*)smem;   // [wave][row n 0..31][32 shorts]
    float*          sO = (float*)smem;            // epilogue overlay (64 x LDO fp32)

    const int tid  = threadIdx.x;
    const int lane = tid & 63;
    const int w    = tid >> 6;
    const int l15  = lane & 15;
    const int quad = lane >> 4;

    const int b   = blockIdx.y;
    const int s0  = blockIdx.x * 64;
    const int h   = blockIdx.z;
    const int kt0 = h * niter;
    const unsigned short* Kfb = Kf + (size_t)b * 262144;
    const unsigned short* Vfb = Vf + (size_t)b * 262144;

    float mxn = MaxPart[b * 64 + lane];
    #pragma unroll
    for (int d = 1; d < 64; d <<= 1) mxn = fmaxf(mxn, __shfl_xor(mxn, d));

    // Q frags from Kf (scaled): row = s0+32w+16qt+l15 -> tile=(s0+32w)>>5, mt=qt
    short8 qf[2][2];
    f32x4 cin[2];
    const int qtile = (s0 + 32 * w) >> 5;
    #pragma unroll
    for (int qt = 0; qt < 2; ++qt) {
        #pragma unroll
        for (int ks = 0; ks < 2; ++ks)
            qf[qt][ks] = *(const short8*)(Kfb + (size_t)(qtile * 4 + qt * 2 + ks) * 512 + lane * 8);
        const float mrow = Norms[(size_t)b * SEQ + s0 + 32 * w + 16 * qt + l15] * mxn;
        cin[qt] = (f32x4){-mrow, -mrow, -mrow, -mrow};
    }

    f32x4 acc_o[2][4];
    #pragma unroll
    for (int qt = 0; qt < 2; ++qt)
        #pragma unroll
        for (int ct = 0; ct < 4; ++ct) acc_o[qt][ct] = (f32x4){0.f, 0.f, 0.f, 0.f};
    f32x4 lp4[2];
    lp4[0] = (f32x4){0.f, 0.f, 0.f, 0.f};
    lp4[1] = (f32x4){0.f, 0.f, 0.f, 0.f};

    // ---- P LDS addresses (wave-private; swizzle verified R8) ----
    const int vkey = (l15 & 3) ^ (l15 >> 2);
    unsigned short* const prow = sP + (w << 10) + (l15 << 5);     // +qt*512
    unsigned short* pw[2];
    #pragma unroll
    for (int mt = 0; mt < 2; ++mt)
        pw[mt] = prow + ((((2 * mt + (quad >> 1)) ^ vkey) << 3) + ((quad & 1) << 2));
    const unsigned short* pr = prow + ((quad ^ vkey) << 3);

    // ---- fragment stream pointers (lane-contiguous 1KB per load) ----
    const unsigned short* kp = Kfb + (size_t)kt0 * 2048 + lane * 8;
    const unsigned short* vp = Vfb + (size_t)kt0 * 2048 + lane * 8;

    for (int it = 0; it < niter; ++it) {
        short8 kf2[2][2], vf[4];
        #pragma unroll
        for (int mt = 0; mt < 2; ++mt)
            #pragma unroll
            for (int ks = 0; ks < 2; ++ks)
                kf2[mt][ks] = *(const short8*)(kp + (mt * 2 + ks) * 512);
        #pragma unroll
        for (int ct = 0; ct < 4; ++ct)
            vf[ct] = *(const short8*)(vp + ct * 512);

        // phase 1: all S-MFMAs (8)
        f32x4 a[2][2];
        #pragma unroll
        for (int qt = 0; qt < 2; ++qt)
            #pragma unroll
            for (int mt = 0; mt < 2; ++mt) {
                f32x4 s = cin[qt];
                s = __builtin_amdgcn_mfma_f32_16x16x32_bf16(kf2[mt][0], qf[qt][0], s, 0, 0, 0);
                s = __builtin_amdgcn_mfma_f32_16x16x32_bf16(kf2[mt][1], qf[qt][1], s, 0, 0, 0);
                a[qt][mt] = s;
            }
        // phase 2: exps + packs + lp partials + P-writes
        #pragma unroll
        for (int qt = 0; qt < 2; ++qt)
            #pragma unroll
            for (int mt = 0; mt < 2; ++mt) {
                const float p0 = fast_exp2(a[qt][mt][0]);
                const float p1 = fast_exp2(a[qt][mt][1]);
                const float p2 = fast_exp2(a[qt][mt][2]);
                const float p3 = fast_exp2(a[qt][mt][3]);
                lp4[qt] += (f32x4){p0, p1, p2, p3};
                const unsigned lo = __builtin_amdgcn_perm(__float_as_uint(p1), __float_as_uint(p0), 0x07060302u);
                const unsigned hi = __builtin_amdgcn_perm(__float_as_uint(p3), __float_as_uint(p2), 0x07060302u);
                *(uint2*)(pw[mt] + qt * 512) = make_uint2(lo, hi);
            }
        // phase 3: P reads, then all PV-MFMAs (8)
        short8 pf[2];
        #pragma unroll
        for (int qt = 0; qt < 2; ++qt)
            pf[qt] = *(const short8*)(pr + qt * 512);
        #pragma unroll
        for (int qt = 0; qt < 2; ++qt)
            #pragma unroll
            for (int ct = 0; ct < 4; ++ct)
                acc_o[qt][ct] = __builtin_amdgcn_mfma_f32_16x16x32_bf16(pf[qt], vf[ct], acc_o[qt][ct], 0, 0, 0);

        kp += 2048;
        vp += 2048;
    }

    float lp[2];
    #pragma unroll
    for (int qt = 0; qt < 2; ++qt) {
        lp[qt] = (lp4[qt][0] + lp4[qt][1]) + (lp4[qt][2] + lp4[qt][3]);
        lp[qt] += __shfl_xor(lp[qt], 16);
        lp[qt] += __shfl_xor(lp[qt], 32);
    }

    if (PARTIAL) {
        if (quad == 0) {
            #pragma unroll
            for (int qt = 0; qt < 2; ++qt)
                (Lbase + (size_t)h * 8 * SEQ)[(size_t)b * SEQ + s0 + 32 * w + 16 * qt + l15] = lp[qt];
        }
    } else {
        #pragma unroll
        for (int qt = 0; qt < 2; ++qt) {
            float inv[4];
            #pragma unroll
            for (int r = 0; r < 4; ++r) inv[r] = fast_rcp(__shfl(lp[qt], 4 * quad + r));
            #pragma unroll
            for (int ct = 0; ct < 4; ++ct)
                #pragma unroll
                for (int r = 0; r < 4; ++r) acc_o[qt][ct][r] *= inv[r];
        }
    }

    __syncthreads();   // all waves done with sP before sO overlay writes
    #pragma unroll
    for (int qt = 0; qt < 2; ++qt)
        #pragma unroll
        for (int ct = 0; ct < 4; ++ct) {
            const int c = 16 * ct + l15;
            #pragma unroll
            for (int r = 0; r < 4; ++r)
                sO[c * LDO + 32 * w + 16 * qt + 4 * quad + r] = acc_o[qt][ct][r];
        }
    __syncthreads();
    const int mw = tid & 15, cg = tid >> 4;
    if (PARTIAL) {
        unsigned short* Op = Obf + (size_t)h * 8 * DIM * SEQ;
        #pragma unroll
        for (int cc = 0; cc < 8; ++cc) {
            const int c = cg + 8 * cc;
            const f32x4 v = *(const f32x4*)(sO + c * LDO + 4 * mw);
            *(ushort4*)(Op + ((size_t)b * DIM + c) * SEQ + s0 + 4 * mw) =
                make_ushort4(f2bf(v.x), f2bf(v.y), f2bf(v.z), f2bf(v.w));
        }
    } else {
        #pragma unroll
        for (int cc = 0; cc < 8; ++cc) {
            const int c = cg + 8 * cc;
            const f32x4 v = *(const f32x4*)(sO + c * LDO + 4 * mw);
            *(f32x4*)(Out + ((size_t)b * DIM + c) * SEQ + s0 + 4 * mw) = v;
        }
    }
}

__global__ __launch_bounds__(256) void combine4(const unsigned short* __restrict__ Obf,
                                                const float* __restrict__ Lp,
                                                float* __restrict__ Out) {
    const int gid = blockIdx.x * 256 + threadIdx.x;
    const size_t base = (size_t)gid * 4;
    const int s = (int)(base & 4095);
    const int b = (int)(base >> 18);
    f32x4 os = (f32x4){0.f, 0.f, 0.f, 0.f};
    f32x4 ls = (f32x4){0.f, 0.f, 0.f, 0.f};
    #pragma unroll
    for (int h = 0; h < 4; ++h) {
        const ushort4 o = *(const ushort4*)(Obf + (size_t)h * 2097152 + base);
        os[0] += bf2f(o.x); os[1] += bf2f(o.y); os[2] += bf2f(o.z); os[3] += bf2f(o.w);
        const f32x4 l = *(const f32x4*)(Lp + (size_t)h * 8 * SEQ + b * SEQ + s);
        #pragma unroll
        for (int i = 0; i < 4; ++i) ls[i] += l[i];
    }
    f32x4 o;
    #pragma unroll
    for (int i = 0; i < 4; ++i) o[i] = os[i] / ls[i];
    *(f32x4*)(Out + base) = o;
}

__global__ __launch_bounds__(256, 2) void attn_fallback(const float* __restrict__ X,
                                                        float* __restrict__ Out) {
    __shared__ __align__(16) unsigned char smem[27648];
    unsigned short* sK = (unsigned short*)smem;
    unsigned short* sV = (unsigned short*)(smem + 9216);
    unsigned short* sP = (unsigned short*)(smem + 18432);
    float*          sO = (float*)smem;
    const int tid  = threadIdx.x;
    const int lane = tid & 63;
    const int w    = tid >> 6;
    const int l15  = lane & 15;
    const int quad = lane >> 4;
    const int b  = blockIdx.y;
    const int s0 = blockIdx.x * 64;
    const float* Xb = X + (size_t)b * DIM * SEQ;
    const int mgrp = tid & 15;
    const int c0   = tid >> 4;

    for (int cc = 0; cc < 4; ++cc) {
        int c = c0 + 16 * cc;
        const f32x4 v = *(const f32x4*)(Xb + (size_t)c * SEQ + s0 + 4 * mgrp);
        sK[(4 * mgrp + 0) * LDB + c] = f2bf(v.x);
        sK[(4 * mgrp + 1) * LDB + c] = f2bf(v.y);
        sK[(4 * mgrp + 2) * LDB + c] = f2bf(v.z);
        sK[(4 * mgrp + 3) * LDB + c] = f2bf(v.w);
    }
    __syncthreads();
    short8 qf0, qf1;
    {
        const int row = 16 * w + l15;
        qf0 = *(const short8*)(sK + row * LDB + quad * 8);
        qf1 = *(const short8*)(sK + row * LDB + 32 + quad * 8);
    }
    __syncthreads();
    f32x4 acc_o[4];
    for (int ct = 0; ct < 4; ++ct) acc_o[ct] = (f32x4){0.f, 0.f, 0.f, 0.f};
    float m_i[4] = {-1e30f, -1e30f, -1e30f, -1e30f};
    float l_i[4] = {0.f, 0.f, 0.f, 0.f};
    for (int kt = 0; kt < SEQ / 64; ++kt) {
        const int m0 = kt * 64;
        for (int cc = 0; cc < 4; ++cc) {
            int c = c0 + 16 * cc;
            const f32x4 v = *(const f32x4*)(Xb + (size_t)c * SEQ + m0 + 4 * mgrp);
            unsigned short h0 = f2bf(v.x), h1 = f2bf(v.y), h2 = f2bf(v.z), h3 = f2bf(v.w);
            *(ushort4*)(sV + c * LDB + 4 * mgrp) = make_ushort4(h0, h1, h2, h3);
            sK[(4 * mgrp + 0) * LDB + c] = h0;
            sK[(4 * mgrp + 1) * LDB + c] = h1;
            sK[(4 * mgrp + 2) * LDB + c] = h2;
            sK[(4 * mgrp + 3) * LDB + c] = h3;
        }
        __syncthreads();
        short8 vf[2][4];
        for (int ks = 0; ks < 2; ++ks)
            for (int ct = 0; ct < 4; ++ct)
                vf[ks][ct] = *(const short8*)(sV + (16 * ct + l15) * LDB + ks * 32 + quad * 8);
        f32x4 acc_s[4];
        for (int mt = 0; mt < 4; ++mt) {
            const int row = 16 * mt + l15;
            const short8 kf0 = *(const short8*)(sK + row * LDB + quad * 8);
            const short8 kf1 = *(const short8*)(sK + row * LDB + 32 + quad * 8);
            f32x4 a = (f32x4){0.f, 0.f, 0.f, 0.f};
            a = __builtin_amdgcn_mfma_f32_16x16x32_bf16(qf0, kf0, a, 0, 0, 0);
            a = __builtin_amdgcn_mfma_f32_16x16x32_bf16(qf1, kf1, a, 0, 0, 0);
            acc_s[mt] = a;
        }
        float alpha[4];
        for (int r = 0; r < 4; ++r) {
            float mx = fmaxf(fmaxf(acc_s[0][r], acc_s[1][r]), fmaxf(acc_s[2][r], acc_s[3][r]));
            mx = fmaxf(mx, __shfl_xor(mx, 1));
            mx = fmaxf(mx, __shfl_xor(mx, 2));
            mx = fmaxf(mx, __shfl_xor(mx, 4));
            mx = fmaxf(mx, __shfl_xor(mx, 8));
            const float mnew = fmaxf(m_i[r], mx);
            alpha[r] = __expf(m_i[r] - mnew);
            m_i[r] = mnew;
        }
        float rowsum[4] = {0.f, 0.f, 0.f, 0.f};
        unsigned short pb[4][4];
        for (int mt = 0; mt < 4; ++mt)
            for (int r = 0; r < 4; ++r) {
                const float p = __expf(acc_s[mt][r] - m_i[r]);
                rowsum[r] += p;
                pb[mt][r] = f2bf(p);
            }
        for (int r = 0; r < 4; ++r) {
            float s = rowsum[r];
            s += __shfl_xor(s, 1);
            s += __shfl_xor(s, 2);
            s += __shfl_xor(s, 4);
            s += __shfl_xor(s, 8);
            l_i[r] = alpha[r] * l_i[r] + s;
        }
        for (int ct = 0; ct < 4; ++ct)
            for (int r = 0; r < 4; ++r)
                acc_o[ct][r] *= alpha[r];
        for (int mt = 0; mt < 4; ++mt)
            for (int r = 0; r < 4; ++r)
                sP[(16 * w + quad * 4 + r) * LDB + l15 + 16 * mt] = pb[mt][r];
        __syncthreads();
        const short8 pf0 = *(const short8*)(sP + (16 * w + l15) * LDB + quad * 8);
        const short8 pf1 = *(const short8*)(sP + (16 * w + l15) * LDB + 32 + quad * 8);
        for (int ct = 0; ct < 4; ++ct) {
            acc_o[ct] = __builtin_amdgcn_mfma_f32_16x16x32_bf16(pf0, vf[0][ct], acc_o[ct], 0, 0, 0);
            acc_o[ct] = __builtin_amdgcn_mfma_f32_16x16x32_bf16(pf1, vf[1][ct], acc_o[ct], 0, 0, 0);
        }
    }
    float inv[4];
    for (int r = 0; r < 4; ++r) inv[r] = 1.f / l_i[r];
    for (int ct = 0; ct < 4; ++ct) {
        const int c = 16 * ct + l15;
        for (int r = 0; r < 4; ++r)
            sO[c * LDO + 16 * w + quad * 4 + r] = acc_o[ct][r] * inv[r];
    }
    __syncthreads();
    for (int cc = 0; cc < 4; ++cc) {
        const int c = c0 + 16 * cc;
        const f32x4 v = *(const f32x4*)(sO + c * LDO + 4 * mgrp);
        *(f32x4*)(Out + (size_t)b * DIM * SEQ + (size_t)c * SEQ + s0 + 4 * mgrp) = v;
    }
}

extern "C" void kernel_launch(void* const* d_in, const int* in_sizes, int n_in,
                              void* d_out, int out_size, void* d_ws, size_t ws_size,
                              hipStream_t stream) {
    const float* X = (const float*)d_in[0];
    float* Out = (float*)d_out;
    const size_t elems = (size_t)8 * SEQ * DIM;               // 2M
    const size_t offVf    = elems * 2;                        // Kf 4MB
    const size_t offNorms = offVf + elems * 2;                // Vf 4MB -> 8MB
    const size_t offMaxP  = offNorms + (size_t)8 * SEQ * 4;   // +128KB
    const size_t offObf   = offMaxP + 8 * 64 * 4;             // +2KB
    const size_t offLp    = offObf + 4 * elems * 2;           // +16MB (4 bf16 slabs)
    const size_t need     = offLp + 4 * (size_t)8 * SEQ * 4;  // ~24.64MB (proven budget)

    if (ws_size >= need) {
        unsigned short* Kf = (unsigned short*)d_ws;
        unsigned short* Vf = (unsigned short*)((char*)d_ws + offVf);
        float* Norms   = (float*)((char*)d_ws + offNorms);
        float* MaxPart = (float*)((char*)d_ws + offMaxP);
        unsigned short* Obf = (unsigned short*)((char*)d_ws + offObf);
        float* Lp = (float*)((char*)d_ws + offLp);
        prepass4<<<dim3(64, 8), 256, 0, stream>>>(X, Kf, Vf, Norms, MaxPart);
        attn_split4<true><<<dim3(64, 8, 4), 128, 0, stream>>>(Kf, Vf, Norms, MaxPart,
                                                              Obf, Lp, nullptr, 32);
        combine4<<<(int)(elems / 1024), 256, 0, stream>>>(Obf, Lp, Out);
    } else {
        attn_fallback<<<dim3(64, 8), 256, 0, stream>>>(X, Out);
    }
}